// Round 8
// baseline (308.449 us; speedup 1.0000x reference)
//
#include <hip/hip_runtime.h>
#include <math.h>

#define FEAT 128
#define BSHIFT 5            // 32 nodes per bucket
#define BNODES 32
#define CAP 2048            // records per sort chunk (16 KB LDS)
#define NBUCK_MAX 2048      // N <= 65536

__device__ __forceinline__ float edge_weight(float d, float scale, float fw, float fb) {
    // scale already includes +1e-6
    float t = fmaxf(d / scale, 0.0f);
    float decay = expf(-t * t);
    float g = 1.0f / (1.0f + expf(-(d * fw + fb)));
    float w = decay * g;
    if (!isfinite(w)) w = 0.0f;
    return w;
}

__device__ __forceinline__ unsigned int bf16_rne(float f) {
    unsigned int b = __float_as_uint(f);
    return (b + 0x7FFFu + ((b >> 16) & 1u)) >> 16;
}

// ---------------- x -> bf16 table ----------------
__global__ __launch_bounds__(256) void convert_kernel(const float4* __restrict__ x4,
                                                      uint2* __restrict__ xbf,
                                                      int n4) {
    int i = blockIdx.x * 256 + threadIdx.x;
    if (i >= n4) return;
    float4 v = x4[i];
    uint2 o;
    o.x = (bf16_rne(v.y) << 16) | bf16_rne(v.x);
    o.y = (bf16_rne(v.w) << 16) | bf16_rne(v.z);
    xbf[i] = o;
}

// ---- count: per-chunk LDS histogram -> coalesced row write (NO global atomics)
__global__ __launch_bounds__(256) void count_kernel(const int* __restrict__ recv,
                                                    int* __restrict__ sub,
                                                    int E, int nbuck, int epb) {
    __shared__ int cnt[NBUCK_MAX];
    int tid = threadIdx.x;
    for (int i = tid; i < nbuck; i += 256) cnt[i] = 0;
    __syncthreads();
    int base = blockIdx.x * epb;
    int end = min(base + epb, E);
    for (int e = base + tid; e < end; e += 256)
        atomicAdd(&cnt[recv[e] >> BSHIFT], 1);
    __syncthreads();
    size_t row = (size_t)blockIdx.x * nbuck;
    for (int i = tid; i < nbuck; i += 256) sub[row + i] = cnt[i];
}

// ---- colscan: per-bucket exclusive prefix over chunks (lane = bucket) ------
__global__ __launch_bounds__(256) void colscan_kernel(int* __restrict__ sub,
                                                      int* __restrict__ tot,
                                                      int nbuck, int nchunk) {
    int b = blockIdx.x * 256 + threadIdx.x;
    if (b >= nbuck) return;
    int run = 0;
    for (int c = 0; c < nchunk; ++c) {
        size_t idx = (size_t)c * nbuck + b;
        int v = sub[idx];
        sub[idx] = run;
        run += v;
    }
    tot[b] = run;
}

// ---- scan: bucket totals -> boff[0..M] ------------------------------------
__global__ __launch_bounds__(1024) void scan_kernel(const int* __restrict__ tot,
                                                    int* __restrict__ boff, int M) {
    __shared__ int part[1024];
    int t = threadIdx.x;
    int chunk = (M + 1023) >> 10;
    int lo = t * chunk, hi = min(lo + chunk, M);
    int s = 0;
    for (int i = lo; i < hi; ++i) s += tot[i];
    part[t] = s;
    __syncthreads();
    for (int d = 1; d < 1024; d <<= 1) {
        int v = (t >= d) ? part[t - d] : 0;
        __syncthreads();
        part[t] += v;
        __syncthreads();
    }
    int run = part[t] - s;
    for (int i = lo; i < hi; ++i) {
        boff[i] = run;
        run += tot[i];
    }
    if (hi == M) boff[M] = run;   // all qualifying threads write the same total
}

// ---- scatter: deterministic bases, single edge pass, LDS-only atomics ------
__global__ __launch_bounds__(256) void bucket_scatter_kernel(
    const int* __restrict__ sender, const int* __restrict__ recv,
    const float* __restrict__ edge_len,
    const float* __restrict__ log_scale, const float* __restrict__ filter_w,
    const float* __restrict__ filter_b,
    const int* __restrict__ sub, const int* __restrict__ boff,
    unsigned long long* __restrict__ buf, int E, int nbuck, int epb) {
    __shared__ int cur[NBUCK_MAX];
    int tid = threadIdx.x;
    size_t row = (size_t)blockIdx.x * nbuck;
    for (int i = tid; i < nbuck; i += 256) cur[i] = boff[i] + sub[row + i];
    __syncthreads();
    int base = blockIdx.x * epb;
    int end = min(base + epb, E);
    float scale = expf(log_scale[0]) + 1e-6f;
    float fw = filter_w[0], fb = filter_b[0];
    for (int e = base + tid; e < end; e += 256) {
        int r = recv[e];
        int s = sender[e];
        float w = edge_weight(edge_len[e], scale, fw, fb);
        int pos = atomicAdd(&cur[r >> BSHIFT], 1);
        unsigned long long rec = ((unsigned long long)__float_as_uint(w) << 32)
                               | (unsigned int)(s & 0xFFFF)
                               | ((unsigned int)(r & (BNODES - 1)) << 16);
        buf[pos] = rec;
    }
}

// ---------------- sort+aggregate: counting sort in LDS, register accumulate -
__device__ __forceinline__ void accum8(float acc[8], uint4 u, float w) {
    acc[0] = fmaf(w, __uint_as_float(u.x << 16), acc[0]);
    acc[1] = fmaf(w, __uint_as_float(u.x & 0xFFFF0000u), acc[1]);
    acc[2] = fmaf(w, __uint_as_float(u.y << 16), acc[2]);
    acc[3] = fmaf(w, __uint_as_float(u.y & 0xFFFF0000u), acc[3]);
    acc[4] = fmaf(w, __uint_as_float(u.z << 16), acc[4]);
    acc[5] = fmaf(w, __uint_as_float(u.z & 0xFFFF0000u), acc[5]);
    acc[6] = fmaf(w, __uint_as_float(u.w << 16), acc[6]);
    acc[7] = fmaf(w, __uint_as_float(u.w & 0xFFFF0000u), acc[7]);
}

__global__ __launch_bounds__(256) void bucket_sort_aggregate_kernel(
    const uint4* __restrict__ xbf4, const unsigned long long* __restrict__ buf,
    const int* __restrict__ boff, uint4* __restrict__ agg_bf4,
    int* __restrict__ deg, int N) {
    __shared__ unsigned long long recS[CAP];   // 16 KB
    __shared__ int cnt32[BNODES];
    __shared__ int segoff[BNODES + 1];

    int b = blockIdx.x;
    int n0 = b << BSHIFT;
    int nEnd = min(n0 + BNODES, N);
    int lo = boff[b], hi = boff[b + 1];
    int tid = threadIdx.x;
    int lane = tid & 15;
    int grp = tid >> 4;

    float acc[2][8] = {{0.f,0.f,0.f,0.f,0.f,0.f,0.f,0.f},
                       {0.f,0.f,0.f,0.f,0.f,0.f,0.f,0.f}};
    int dcnt[2] = {0, 0};

    for (int pos = lo; pos < hi; pos += CAP) {
        int cnt = min(CAP, hi - pos);
        if (tid < BNODES) cnt32[tid] = 0;
        __syncthreads();

        unsigned long long rec[CAP / 256];
        int rnk[CAP / 256];
        int locl[CAP / 256];
#pragma unroll
        for (int k = 0; k < CAP / 256; ++k) {
            int i = k * 256 + tid;
            if (i < cnt) {
                unsigned long long r = buf[pos + i];
                int l = ((unsigned int)r >> 16) & (BNODES - 1);
                rec[k] = r;
                locl[k] = l;
                rnk[k] = atomicAdd(&cnt32[l], 1);
            }
        }
        __syncthreads();
        if (tid == 0) {
            int run = 0;
#pragma unroll
            for (int l = 0; l < BNODES; ++l) { segoff[l] = run; run += cnt32[l]; }
            segoff[BNODES] = run;
        }
        __syncthreads();
#pragma unroll
        for (int k = 0; k < CAP / 256; ++k) {
            int i = k * 256 + tid;
            if (i < cnt) recS[segoff[locl[k]] + rnk[k]] = rec[k];
        }
        __syncthreads();

        // accumulate: group handles local nodes grp and grp+16; 4-deep unroll
#pragma unroll
        for (int which = 0; which < 2; ++which) {
            int l = grp + which * 16;
            int s0 = segoff[l], s1 = segoff[l + 1];
            dcnt[which] += s1 - s0;
            int i = s0;
            for (; i + 4 <= s1; i += 4) {
                unsigned long long r0 = recS[i];
                unsigned long long r1 = recS[i + 1];
                unsigned long long r2 = recS[i + 2];
                unsigned long long r3 = recS[i + 3];
                float w0 = __uint_as_float((unsigned int)(r0 >> 32));
                float w1 = __uint_as_float((unsigned int)(r1 >> 32));
                float w2 = __uint_as_float((unsigned int)(r2 >> 32));
                float w3 = __uint_as_float((unsigned int)(r3 >> 32));
                int s0i = (unsigned int)r0 & 0xFFFF;
                int s1i = (unsigned int)r1 & 0xFFFF;
                int s2i = (unsigned int)r2 & 0xFFFF;
                int s3i = (unsigned int)r3 & 0xFFFF;
                uint4 u0 = xbf4[(size_t)s0i * 16 + lane];
                uint4 u1 = xbf4[(size_t)s1i * 16 + lane];
                uint4 u2 = xbf4[(size_t)s2i * 16 + lane];
                uint4 u3 = xbf4[(size_t)s3i * 16 + lane];
                accum8(acc[which], u0, w0);
                accum8(acc[which], u1, w1);
                accum8(acc[which], u2, w2);
                accum8(acc[which], u3, w3);
            }
            for (; i < s1; ++i) {
                unsigned long long ra = recS[i];
                float wa = __uint_as_float((unsigned int)(ra >> 32));
                int sa = (unsigned int)ra & 0xFFFF;
                uint4 ua = xbf4[(size_t)sa * 16 + lane];
                accum8(acc[which], ua, wa);
            }
        }
        __syncthreads();   // before next chunk overwrites recS
    }

    // writeout: bf16-pack; lane owns features lane*8..lane*8+7
#pragma unroll
    for (int which = 0; which < 2; ++which) {
        int n = n0 + grp + which * 16;
        if (n < nEnd) {
            uint4 o;
            o.x = (bf16_rne(acc[which][1]) << 16) | bf16_rne(acc[which][0]);
            o.y = (bf16_rne(acc[which][3]) << 16) | bf16_rne(acc[which][2]);
            o.z = (bf16_rne(acc[which][5]) << 16) | bf16_rne(acc[which][4]);
            o.w = (bf16_rne(acc[which][7]) << 16) | bf16_rne(acc[which][6]);
            agg_bf4[(size_t)n * 16 + lane] = o;
            if (lane == 0) deg[n] = dcnt[which];
        }
    }
}

// ---------------- finalize: tiled GEMM, out = x + (agg/deg) @ W --------------
__global__ __launch_bounds__(256) void finalize_kernel(
    const float* __restrict__ x, const uint4* __restrict__ agg_bf4,
    const int* __restrict__ deg, const float* __restrict__ Wm,
    float* __restrict__ out, int N) {
    __shared__ float aggS[64 * 128];  // 32 KB
    __shared__ float Ws[128 * 64];    // 32 KB
    const int n0 = blockIdx.x * 64;

    for (int i = threadIdx.x; i < 64 * 16; i += 256) {
        int r = i >> 4;
        int q = i & 15;
        int n = n0 + r;
        uint4 u = make_uint4(0u, 0u, 0u, 0u);
        if (n < N) u = agg_bf4[(size_t)n * 16 + q];
        float4 f0, f1;
        f0.x = __uint_as_float(u.x << 16);
        f0.y = __uint_as_float(u.x & 0xFFFF0000u);
        f0.z = __uint_as_float(u.y << 16);
        f0.w = __uint_as_float(u.y & 0xFFFF0000u);
        f1.x = __uint_as_float(u.z << 16);
        f1.y = __uint_as_float(u.z & 0xFFFF0000u);
        f1.z = __uint_as_float(u.w << 16);
        f1.w = __uint_as_float(u.w & 0xFFFF0000u);
        int m = (r >> 2) & 7;
        ((float4*)aggS)[r * 32 + ((2 * q) ^ m)] = f0;
        ((float4*)aggS)[r * 32 + ((2 * q + 1) ^ m)] = f1;
    }

    const int tc = threadIdx.x & 15;
    const int tr = threadIdx.x >> 4;

    float invd[4];
#pragma unroll
    for (int i = 0; i < 4; ++i) {
        int n = n0 + 4 * tr + i;
        float degf = 1.0f;
        if (n < N) degf = fmaxf((float)deg[n], 1.0f);
        invd[i] = 1.0f / degf;
    }

    for (int h = 0; h < 2; ++h) {
        for (int i = threadIdx.x; i < 128 * 16; i += 256) {
            int k = i >> 4;
            int j4 = i & 15;
            ((float4*)Ws)[k * 16 + j4] = ((const float4*)Wm)[k * 32 + h * 16 + j4];
        }
        __syncthreads();

        float acc[4][4];
#pragma unroll
        for (int i = 0; i < 4; ++i)
#pragma unroll
            for (int c = 0; c < 4; ++c) acc[i][c] = 0.f;

#pragma unroll 4
        for (int k0 = 0; k0 < 128; k0 += 4) {
            float4 ar4[4];
            const int chunk = (k0 >> 2) ^ (tr & 7);
#pragma unroll
            for (int i = 0; i < 4; ++i) {
                int r = 4 * tr + i;
                ar4[i] = ((const float4*)aggS)[r * 32 + chunk];
            }
            float4 wv4[4];
#pragma unroll
            for (int kk = 0; kk < 4; ++kk)
                wv4[kk] = *(const float4*)&Ws[(k0 + kk) * 64 + tc * 4];

            float wvv[4][4];
#pragma unroll
            for (int kk = 0; kk < 4; ++kk) {
                wvv[kk][0] = wv4[kk].x; wvv[kk][1] = wv4[kk].y;
                wvv[kk][2] = wv4[kk].z; wvv[kk][3] = wv4[kk].w;
            }
#pragma unroll
            for (int i = 0; i < 4; ++i) {
                float av[4] = {ar4[i].x, ar4[i].y, ar4[i].z, ar4[i].w};
#pragma unroll
                for (int kk = 0; kk < 4; ++kk)
#pragma unroll
                    for (int c = 0; c < 4; ++c)
                        acc[i][c] = fmaf(av[kk], wvv[kk][c], acc[i][c]);
            }
        }

#pragma unroll
        for (int i = 0; i < 4; ++i) {
            int n = n0 + 4 * tr + i;
            if (n < N) {
                size_t base = (size_t)n * FEAT + h * 64 + tc * 4;
                float4 xv = *(const float4*)&x[base];
                float4 o;
                o.x = xv.x + invd[i] * acc[i][0];
                o.y = xv.y + invd[i] * acc[i][1];
                o.z = xv.z + invd[i] * acc[i][2];
                o.w = xv.w + invd[i] * acc[i][3];
                *(float4*)&out[base] = o;
            }
        }
        __syncthreads();
    }
}

// ---------------- fallback (atomic path) ---------------
__global__ __launch_bounds__(256) void scatter_fallback(
    const float4* __restrict__ x4, const int* __restrict__ sender,
    const int* __restrict__ receiver, const float* __restrict__ edge_len,
    const float* __restrict__ log_scale, const float* __restrict__ filter_w,
    const float* __restrict__ filter_b, float* __restrict__ agg,
    float* __restrict__ deg, int E) {
    int gid = blockIdx.x * 256 + threadIdx.x;
    int e = gid >> 5;
    if (e >= E) return;
    int lane = gid & 31;
    int s = sender[e];
    int r = receiver[e];
    float scale = expf(log_scale[0]) + 1e-6f;
    float w = edge_weight(edge_len[e], scale, filter_w[0], filter_b[0]);
    float4 xv = x4[s * (FEAT / 4) + lane];
    float* dst = agg + (size_t)r * FEAT + lane * 4;
    unsafeAtomicAdd(dst + 0, w * xv.x);
    unsafeAtomicAdd(dst + 1, w * xv.y);
    unsafeAtomicAdd(dst + 2, w * xv.z);
    unsafeAtomicAdd(dst + 3, w * xv.w);
    if (lane == 0) unsafeAtomicAdd(&deg[r], 1.0f);
}

__global__ __launch_bounds__(256) void finalize_fallback(
    const float* __restrict__ x, const float* __restrict__ agg,
    const float* __restrict__ deg, const float* __restrict__ Wm,
    float* __restrict__ out, int N) {
    __shared__ float Wsf[FEAT * FEAT];
    for (int i = threadIdx.x * 4; i < FEAT * FEAT; i += 256 * 4)
        *(float4*)&Wsf[i] = *(const float4*)&Wm[i];
    __syncthreads();
    int half = threadIdx.x >> 7;
    int j = threadIdx.x & (FEAT - 1);
    for (int n0 = blockIdx.x * 2; n0 < N; n0 += gridDim.x * 2) {
        int n = n0 + half;
        if (n < N) {
            const float* arow = agg + (size_t)n * FEAT;
            float acc = 0.0f;
#pragma unroll 16
            for (int k = 0; k < FEAT; ++k) acc = fmaf(arow[k], Wsf[k * FEAT + j], acc);
            float invd = 1.0f / fmaxf(deg[n], 1.0f);
            size_t idx = (size_t)n * FEAT + j;
            out[idx] = x[idx] + invd * acc;
        }
    }
}

extern "C" void kernel_launch(void* const* d_in, const int* in_sizes, int n_in,
                              void* d_out, int out_size, void* d_ws, size_t ws_size,
                              hipStream_t stream) {
    const float* x         = (const float*)d_in[0];
    const int*   ei        = (const int*)d_in[1];
    const float* edge_len  = (const float*)d_in[2];
    const float* W_mix     = (const float*)d_in[3];
    const float* log_scale = (const float*)d_in[4];
    const float* filter_w  = (const float*)d_in[5];
    const float* filter_b  = (const float*)d_in[6];
    float* out = (float*)d_out;

    const int N = in_sizes[0] / FEAT;
    const int E = in_sizes[1] / 2;
    const int* sender   = ei;
    const int* receiver = ei + E;
    const int nbuck = (N + BNODES - 1) >> BSHIFT;

    // fixed-size pieces
    size_t xbf_bytes  = (size_t)N * FEAT * 2;
    size_t aggb_bytes = (size_t)N * FEAT * 2;
    size_t buf_bytes  = (size_t)E * 8;
    size_t tot_bytes  = (((size_t)nbuck * 4) + 63) & ~(size_t)63;
    size_t boff_bytes = (((size_t)(nbuck + 1) * 4) + 63) & ~(size_t)63;
    size_t deg_bytes  = (((size_t)N * 4) + 63) & ~(size_t)63;
    size_t fixed = xbf_bytes + aggb_bytes + buf_bytes + tot_bytes + boff_bytes +
                   deg_bytes;

    // pick EPB adaptively: smaller chunks = more parallelism, bigger sub matrix
    int epb = 0, nchunk = 0;
    size_t sub_bytes = 0;
    const int epb_opts[3] = {4096, 8192, 16384};
    for (int oi = 0; oi < 3; ++oi) {
        int cand = epb_opts[oi];
        int nc = (E + cand - 1) / cand;
        size_t sb = (((size_t)nc * nbuck * 4) + 63) & ~(size_t)63;
        if (fixed + sb <= ws_size) { epb = cand; nchunk = nc; sub_bytes = sb; break; }
    }

    if (epb != 0 && N <= 65536) {
        char* p = (char*)d_ws;
        uint2* xbf    = (uint2*)p;                        p += xbf_bytes;
        uint4* agg_bf = (uint4*)p;                        p += aggb_bytes;
        unsigned long long* buf = (unsigned long long*)p; p += buf_bytes;
        int* sub  = (int*)p;                              p += sub_bytes;
        int* tot  = (int*)p;                              p += tot_bytes;
        int* boff = (int*)p;                              p += boff_bytes;
        int* deg  = (int*)p;

        int cblocks = (N * (FEAT / 4) + 255) / 256;
        convert_kernel<<<cblocks, 256, 0, stream>>>((const float4*)x, xbf,
                                                    N * (FEAT / 4));
        count_kernel<<<nchunk, 256, 0, stream>>>(receiver, sub, E, nbuck, epb);
        colscan_kernel<<<(nbuck + 255) / 256, 256, 0, stream>>>(sub, tot,
                                                                nbuck, nchunk);
        scan_kernel<<<1, 1024, 0, stream>>>(tot, boff, nbuck);
        bucket_scatter_kernel<<<nchunk, 256, 0, stream>>>(
            sender, receiver, edge_len, log_scale, filter_w, filter_b,
            sub, boff, buf, E, nbuck, epb);
        bucket_sort_aggregate_kernel<<<nbuck, 256, 0, stream>>>(
            (const uint4*)xbf, buf, boff, agg_bf, deg, N);
        int fblocks = (N + 63) / 64;
        finalize_kernel<<<fblocks, 256, 0, stream>>>(x, (const uint4*)agg_bf, deg,
                                                     W_mix, out, N);
    } else {
        float* agg = (float*)d_ws;
        float* degf = agg + (size_t)N * FEAT;
        hipMemsetAsync(agg, 0, ((size_t)N * FEAT + N) * sizeof(float), stream);
        int sblocks = (E * 32 + 255) / 256;
        scatter_fallback<<<sblocks, 256, 0, stream>>>(
            (const float4*)x, sender, receiver, edge_len,
            log_scale, filter_w, filter_b, agg, degf, E);
        finalize_fallback<<<512, 256, 0, stream>>>(x, agg, degf, W_mix, out, N);
    }
}

// Round 9
// 231.841 us; speedup vs baseline: 1.3304x; 1.3304x over previous
//
#include <hip/hip_runtime.h>
#include <math.h>

#define FEAT 128
#define BSHIFT 5            // 32 nodes per bucket
#define BNODES 32
#define CAP 2048            // records per sort chunk (16 KB LDS)
#define NBUCK_MAX 2048      // N <= 65536

__device__ __forceinline__ float edge_weight(float d, float scale, float fw, float fb) {
    // scale already includes +1e-6
    float t = fmaxf(d / scale, 0.0f);
    float decay = expf(-t * t);
    float g = 1.0f / (1.0f + expf(-(d * fw + fb)));
    float w = decay * g;
    if (!isfinite(w)) w = 0.0f;
    return w;
}

__device__ __forceinline__ unsigned int bf16_rne(float f) {
    unsigned int b = __float_as_uint(f);
    return (b + 0x7FFFu + ((b >> 16) & 1u)) >> 16;
}

// ---------------- x -> bf16 table ----------------
__global__ __launch_bounds__(256) void convert_kernel(const float4* __restrict__ x4,
                                                      uint2* __restrict__ xbf,
                                                      int n4) {
    int i = blockIdx.x * 256 + threadIdx.x;
    if (i >= n4) return;
    float4 v = x4[i];
    uint2 o;
    o.x = (bf16_rne(v.y) << 16) | bf16_rne(v.x);
    o.y = (bf16_rne(v.w) << 16) | bf16_rne(v.z);
    xbf[i] = o;
}

// ---- count: per-chunk LDS histogram -> coalesced row write (NO global atomics)
__global__ __launch_bounds__(256) void count_kernel(const int* __restrict__ recv,
                                                    int* __restrict__ sub,
                                                    int E, int nbuck, int epb) {
    __shared__ int cnt[NBUCK_MAX];
    int tid = threadIdx.x;
    for (int i = tid; i < nbuck; i += 256) cnt[i] = 0;
    __syncthreads();
    int base = blockIdx.x * epb;
    int end = min(base + epb, E);
    for (int e = base + tid; e < end; e += 256)
        atomicAdd(&cnt[recv[e] >> BSHIFT], 1);
    __syncthreads();
    size_t row = (size_t)blockIdx.x * nbuck;
    for (int i = tid; i < nbuck; i += 256) sub[row + i] = cnt[i];
}

// ---- colscan: ONE BLOCK PER BUCKET, LDS scan over chunk counts -------------
// (R8's one-thread-per-bucket version was 89 us at 0.26% occupancy.)
__global__ __launch_bounds__(256) void colscan_kernel(int* __restrict__ sub,
                                                      int* __restrict__ tot,
                                                      int nbuck, int nchunk) {
    __shared__ int vals[256];
    int b = blockIdx.x;
    int tid = threadIdx.x;
    int carry = 0;
    for (int c0 = 0; c0 < nchunk; c0 += 256) {
        int c = c0 + tid;
        int v = (c < nchunk) ? sub[(size_t)c * nbuck + b] : 0;
        vals[tid] = v;
        __syncthreads();
        for (int d = 1; d < 256; d <<= 1) {
            int t = (tid >= d) ? vals[tid - d] : 0;
            __syncthreads();
            vals[tid] += t;
            __syncthreads();
        }
        int excl = vals[tid] - v;
        if (c < nchunk) sub[(size_t)c * nbuck + b] = carry + excl;
        int btot = vals[255];
        __syncthreads();   // protect vals before next tile
        carry += btot;
    }
    if (tid == 0) tot[b] = carry;
}

// ---- scan: bucket totals -> boff[0..M] ------------------------------------
__global__ __launch_bounds__(1024) void scan_kernel(const int* __restrict__ tot,
                                                    int* __restrict__ boff, int M) {
    __shared__ int part[1024];
    int t = threadIdx.x;
    int chunk = (M + 1023) >> 10;
    int lo = t * chunk, hi = min(lo + chunk, M);
    int s = 0;
    for (int i = lo; i < hi; ++i) s += tot[i];
    part[t] = s;
    __syncthreads();
    for (int d = 1; d < 1024; d <<= 1) {
        int v = (t >= d) ? part[t - d] : 0;
        __syncthreads();
        part[t] += v;
        __syncthreads();
    }
    int run = part[t] - s;
    for (int i = lo; i < hi; ++i) {
        boff[i] = run;
        run += tot[i];
    }
    if (hi == M) boff[M] = run;   // all qualifying threads write the same total
}

// ---- scatter: deterministic bases, single edge pass, LDS-only atomics ------
__global__ __launch_bounds__(256) void bucket_scatter_kernel(
    const int* __restrict__ sender, const int* __restrict__ recv,
    const float* __restrict__ edge_len,
    const float* __restrict__ log_scale, const float* __restrict__ filter_w,
    const float* __restrict__ filter_b,
    const int* __restrict__ sub, const int* __restrict__ boff,
    unsigned long long* __restrict__ buf, int E, int nbuck, int epb) {
    __shared__ int cur[NBUCK_MAX];
    int tid = threadIdx.x;
    size_t row = (size_t)blockIdx.x * nbuck;
    for (int i = tid; i < nbuck; i += 256) cur[i] = boff[i] + sub[row + i];
    __syncthreads();
    int base = blockIdx.x * epb;
    int end = min(base + epb, E);
    float scale = expf(log_scale[0]) + 1e-6f;
    float fw = filter_w[0], fb = filter_b[0];
    for (int e = base + tid; e < end; e += 256) {
        int r = recv[e];
        int s = sender[e];
        float w = edge_weight(edge_len[e], scale, fw, fb);
        int pos = atomicAdd(&cur[r >> BSHIFT], 1);
        unsigned long long rec = ((unsigned long long)__float_as_uint(w) << 32)
                               | (unsigned int)(s & 0xFFFF)
                               | ((unsigned int)(r & (BNODES - 1)) << 16);
        buf[pos] = rec;
    }
}

// ---------------- sort+aggregate: counting sort in LDS, register accumulate -
__device__ __forceinline__ void accum8(float acc[8], uint4 u, float w) {
    acc[0] = fmaf(w, __uint_as_float(u.x << 16), acc[0]);
    acc[1] = fmaf(w, __uint_as_float(u.x & 0xFFFF0000u), acc[1]);
    acc[2] = fmaf(w, __uint_as_float(u.y << 16), acc[2]);
    acc[3] = fmaf(w, __uint_as_float(u.y & 0xFFFF0000u), acc[3]);
    acc[4] = fmaf(w, __uint_as_float(u.z << 16), acc[4]);
    acc[5] = fmaf(w, __uint_as_float(u.z & 0xFFFF0000u), acc[5]);
    acc[6] = fmaf(w, __uint_as_float(u.w << 16), acc[6]);
    acc[7] = fmaf(w, __uint_as_float(u.w & 0xFFFF0000u), acc[7]);
}

__global__ __launch_bounds__(256) void bucket_sort_aggregate_kernel(
    const uint4* __restrict__ xbf4, const unsigned long long* __restrict__ buf,
    const int* __restrict__ boff, uint4* __restrict__ agg_bf4,
    int* __restrict__ deg, int N) {
    __shared__ unsigned long long recS[CAP];   // 16 KB
    __shared__ int cnt32[BNODES];
    __shared__ int segoff[BNODES + 1];

    int b = blockIdx.x;
    int n0 = b << BSHIFT;
    int nEnd = min(n0 + BNODES, N);
    int lo = boff[b], hi = boff[b + 1];
    int tid = threadIdx.x;
    int lane = tid & 15;
    int grp = tid >> 4;

    float acc[2][8] = {{0.f,0.f,0.f,0.f,0.f,0.f,0.f,0.f},
                       {0.f,0.f,0.f,0.f,0.f,0.f,0.f,0.f}};
    int dcnt[2] = {0, 0};

    for (int pos = lo; pos < hi; pos += CAP) {
        int cnt = min(CAP, hi - pos);
        if (tid < BNODES) cnt32[tid] = 0;
        __syncthreads();

        unsigned long long rec[CAP / 256];
        int rnk[CAP / 256];
        int locl[CAP / 256];
#pragma unroll
        for (int k = 0; k < CAP / 256; ++k) {
            int i = k * 256 + tid;
            if (i < cnt) {
                unsigned long long r = buf[pos + i];
                int l = ((unsigned int)r >> 16) & (BNODES - 1);
                rec[k] = r;
                locl[k] = l;
                rnk[k] = atomicAdd(&cnt32[l], 1);
            }
        }
        __syncthreads();
        if (tid == 0) {
            int run = 0;
#pragma unroll
            for (int l = 0; l < BNODES; ++l) { segoff[l] = run; run += cnt32[l]; }
            segoff[BNODES] = run;
        }
        __syncthreads();
#pragma unroll
        for (int k = 0; k < CAP / 256; ++k) {
            int i = k * 256 + tid;
            if (i < cnt) recS[segoff[locl[k]] + rnk[k]] = rec[k];
        }
        __syncthreads();

        // accumulate: group handles local nodes grp and grp+16; 4-deep unroll
#pragma unroll
        for (int which = 0; which < 2; ++which) {
            int l = grp + which * 16;
            int s0 = segoff[l], s1 = segoff[l + 1];
            dcnt[which] += s1 - s0;
            int i = s0;
            for (; i + 4 <= s1; i += 4) {
                unsigned long long r0 = recS[i];
                unsigned long long r1 = recS[i + 1];
                unsigned long long r2 = recS[i + 2];
                unsigned long long r3 = recS[i + 3];
                float w0 = __uint_as_float((unsigned int)(r0 >> 32));
                float w1 = __uint_as_float((unsigned int)(r1 >> 32));
                float w2 = __uint_as_float((unsigned int)(r2 >> 32));
                float w3 = __uint_as_float((unsigned int)(r3 >> 32));
                int s0i = (unsigned int)r0 & 0xFFFF;
                int s1i = (unsigned int)r1 & 0xFFFF;
                int s2i = (unsigned int)r2 & 0xFFFF;
                int s3i = (unsigned int)r3 & 0xFFFF;
                uint4 u0 = xbf4[(size_t)s0i * 16 + lane];
                uint4 u1 = xbf4[(size_t)s1i * 16 + lane];
                uint4 u2 = xbf4[(size_t)s2i * 16 + lane];
                uint4 u3 = xbf4[(size_t)s3i * 16 + lane];
                accum8(acc[which], u0, w0);
                accum8(acc[which], u1, w1);
                accum8(acc[which], u2, w2);
                accum8(acc[which], u3, w3);
            }
            for (; i < s1; ++i) {
                unsigned long long ra = recS[i];
                float wa = __uint_as_float((unsigned int)(ra >> 32));
                int sa = (unsigned int)ra & 0xFFFF;
                uint4 ua = xbf4[(size_t)sa * 16 + lane];
                accum8(acc[which], ua, wa);
            }
        }
        __syncthreads();   // before next chunk overwrites recS
    }

    // writeout: bf16-pack; lane owns features lane*8..lane*8+7
#pragma unroll
    for (int which = 0; which < 2; ++which) {
        int n = n0 + grp + which * 16;
        if (n < nEnd) {
            uint4 o;
            o.x = (bf16_rne(acc[which][1]) << 16) | bf16_rne(acc[which][0]);
            o.y = (bf16_rne(acc[which][3]) << 16) | bf16_rne(acc[which][2]);
            o.z = (bf16_rne(acc[which][5]) << 16) | bf16_rne(acc[which][4]);
            o.w = (bf16_rne(acc[which][7]) << 16) | bf16_rne(acc[which][6]);
            agg_bf4[(size_t)n * 16 + lane] = o;
            if (lane == 0) deg[n] = dcnt[which];
        }
    }
}

// ---------------- finalize: tiled GEMM, out = x + (agg/deg) @ W --------------
__global__ __launch_bounds__(256) void finalize_kernel(
    const float* __restrict__ x, const uint4* __restrict__ agg_bf4,
    const int* __restrict__ deg, const float* __restrict__ Wm,
    float* __restrict__ out, int N) {
    __shared__ float aggS[64 * 128];  // 32 KB
    __shared__ float Ws[128 * 64];    // 32 KB
    const int n0 = blockIdx.x * 64;

    for (int i = threadIdx.x; i < 64 * 16; i += 256) {
        int r = i >> 4;
        int q = i & 15;
        int n = n0 + r;
        uint4 u = make_uint4(0u, 0u, 0u, 0u);
        if (n < N) u = agg_bf4[(size_t)n * 16 + q];
        float4 f0, f1;
        f0.x = __uint_as_float(u.x << 16);
        f0.y = __uint_as_float(u.x & 0xFFFF0000u);
        f0.z = __uint_as_float(u.y << 16);
        f0.w = __uint_as_float(u.y & 0xFFFF0000u);
        f1.x = __uint_as_float(u.z << 16);
        f1.y = __uint_as_float(u.z & 0xFFFF0000u);
        f1.z = __uint_as_float(u.w << 16);
        f1.w = __uint_as_float(u.w & 0xFFFF0000u);
        int m = (r >> 2) & 7;
        ((float4*)aggS)[r * 32 + ((2 * q) ^ m)] = f0;
        ((float4*)aggS)[r * 32 + ((2 * q + 1) ^ m)] = f1;
    }

    const int tc = threadIdx.x & 15;
    const int tr = threadIdx.x >> 4;

    float invd[4];
#pragma unroll
    for (int i = 0; i < 4; ++i) {
        int n = n0 + 4 * tr + i;
        float degf = 1.0f;
        if (n < N) degf = fmaxf((float)deg[n], 1.0f);
        invd[i] = 1.0f / degf;
    }

    for (int h = 0; h < 2; ++h) {
        for (int i = threadIdx.x; i < 128 * 16; i += 256) {
            int k = i >> 4;
            int j4 = i & 15;
            ((float4*)Ws)[k * 16 + j4] = ((const float4*)Wm)[k * 32 + h * 16 + j4];
        }
        __syncthreads();

        float acc[4][4];
#pragma unroll
        for (int i = 0; i < 4; ++i)
#pragma unroll
            for (int c = 0; c < 4; ++c) acc[i][c] = 0.f;

#pragma unroll 4
        for (int k0 = 0; k0 < 128; k0 += 4) {
            float4 ar4[4];
            const int chunk = (k0 >> 2) ^ (tr & 7);
#pragma unroll
            for (int i = 0; i < 4; ++i) {
                int r = 4 * tr + i;
                ar4[i] = ((const float4*)aggS)[r * 32 + chunk];
            }
            float4 wv4[4];
#pragma unroll
            for (int kk = 0; kk < 4; ++kk)
                wv4[kk] = *(const float4*)&Ws[(k0 + kk) * 64 + tc * 4];

            float wvv[4][4];
#pragma unroll
            for (int kk = 0; kk < 4; ++kk) {
                wvv[kk][0] = wv4[kk].x; wvv[kk][1] = wv4[kk].y;
                wvv[kk][2] = wv4[kk].z; wvv[kk][3] = wv4[kk].w;
            }
#pragma unroll
            for (int i = 0; i < 4; ++i) {
                float av[4] = {ar4[i].x, ar4[i].y, ar4[i].z, ar4[i].w};
#pragma unroll
                for (int kk = 0; kk < 4; ++kk)
#pragma unroll
                    for (int c = 0; c < 4; ++c)
                        acc[i][c] = fmaf(av[kk], wvv[kk][c], acc[i][c]);
            }
        }

#pragma unroll
        for (int i = 0; i < 4; ++i) {
            int n = n0 + 4 * tr + i;
            if (n < N) {
                size_t base = (size_t)n * FEAT + h * 64 + tc * 4;
                float4 xv = *(const float4*)&x[base];
                float4 o;
                o.x = xv.x + invd[i] * acc[i][0];
                o.y = xv.y + invd[i] * acc[i][1];
                o.z = xv.z + invd[i] * acc[i][2];
                o.w = xv.w + invd[i] * acc[i][3];
                *(float4*)&out[base] = o;
            }
        }
        __syncthreads();
    }
}

// ---------------- fallback (atomic path) ---------------
__global__ __launch_bounds__(256) void scatter_fallback(
    const float4* __restrict__ x4, const int* __restrict__ sender,
    const int* __restrict__ receiver, const float* __restrict__ edge_len,
    const float* __restrict__ log_scale, const float* __restrict__ filter_w,
    const float* __restrict__ filter_b, float* __restrict__ agg,
    float* __restrict__ deg, int E) {
    int gid = blockIdx.x * 256 + threadIdx.x;
    int e = gid >> 5;
    if (e >= E) return;
    int lane = gid & 31;
    int s = sender[e];
    int r = receiver[e];
    float scale = expf(log_scale[0]) + 1e-6f;
    float w = edge_weight(edge_len[e], scale, filter_w[0], filter_b[0]);
    float4 xv = x4[s * (FEAT / 4) + lane];
    float* dst = agg + (size_t)r * FEAT + lane * 4;
    unsafeAtomicAdd(dst + 0, w * xv.x);
    unsafeAtomicAdd(dst + 1, w * xv.y);
    unsafeAtomicAdd(dst + 2, w * xv.z);
    unsafeAtomicAdd(dst + 3, w * xv.w);
    if (lane == 0) unsafeAtomicAdd(&deg[r], 1.0f);
}

__global__ __launch_bounds__(256) void finalize_fallback(
    const float* __restrict__ x, const float* __restrict__ agg,
    const float* __restrict__ deg, const float* __restrict__ Wm,
    float* __restrict__ out, int N) {
    __shared__ float Wsf[FEAT * FEAT];
    for (int i = threadIdx.x * 4; i < FEAT * FEAT; i += 256 * 4)
        *(float4*)&Wsf[i] = *(const float4*)&Wm[i];
    __syncthreads();
    int half = threadIdx.x >> 7;
    int j = threadIdx.x & (FEAT - 1);
    for (int n0 = blockIdx.x * 2; n0 < N; n0 += gridDim.x * 2) {
        int n = n0 + half;
        if (n < N) {
            const float* arow = agg + (size_t)n * FEAT;
            float acc = 0.0f;
#pragma unroll 16
            for (int k = 0; k < FEAT; ++k) acc = fmaf(arow[k], Wsf[k * FEAT + j], acc);
            float invd = 1.0f / fmaxf(deg[n], 1.0f);
            size_t idx = (size_t)n * FEAT + j;
            out[idx] = x[idx] + invd * acc;
        }
    }
}

extern "C" void kernel_launch(void* const* d_in, const int* in_sizes, int n_in,
                              void* d_out, int out_size, void* d_ws, size_t ws_size,
                              hipStream_t stream) {
    const float* x         = (const float*)d_in[0];
    const int*   ei        = (const int*)d_in[1];
    const float* edge_len  = (const float*)d_in[2];
    const float* W_mix     = (const float*)d_in[3];
    const float* log_scale = (const float*)d_in[4];
    const float* filter_w  = (const float*)d_in[5];
    const float* filter_b  = (const float*)d_in[6];
    float* out = (float*)d_out;

    const int N = in_sizes[0] / FEAT;
    const int E = in_sizes[1] / 2;
    const int* sender   = ei;
    const int* receiver = ei + E;
    const int nbuck = (N + BNODES - 1) >> BSHIFT;

    // fixed-size pieces
    size_t xbf_bytes  = (size_t)N * FEAT * 2;
    size_t aggb_bytes = (size_t)N * FEAT * 2;
    size_t buf_bytes  = (size_t)E * 8;
    size_t tot_bytes  = (((size_t)nbuck * 4) + 63) & ~(size_t)63;
    size_t boff_bytes = (((size_t)(nbuck + 1) * 4) + 63) & ~(size_t)63;
    size_t deg_bytes  = (((size_t)N * 4) + 63) & ~(size_t)63;
    size_t fixed = xbf_bytes + aggb_bytes + buf_bytes + tot_bytes + boff_bytes +
                   deg_bytes;

    // pick EPB adaptively: smaller chunks = more parallelism, bigger sub matrix
    int epb = 0, nchunk = 0;
    size_t sub_bytes = 0;
    const int epb_opts[3] = {4096, 8192, 16384};
    for (int oi = 0; oi < 3; ++oi) {
        int cand = epb_opts[oi];
        int nc = (E + cand - 1) / cand;
        size_t sb = (((size_t)nc * nbuck * 4) + 63) & ~(size_t)63;
        if (fixed + sb <= ws_size) { epb = cand; nchunk = nc; sub_bytes = sb; break; }
    }

    if (epb != 0 && N <= 65536) {
        char* p = (char*)d_ws;
        uint2* xbf    = (uint2*)p;                        p += xbf_bytes;
        uint4* agg_bf = (uint4*)p;                        p += aggb_bytes;
        unsigned long long* buf = (unsigned long long*)p; p += buf_bytes;
        int* sub  = (int*)p;                              p += sub_bytes;
        int* tot  = (int*)p;                              p += tot_bytes;
        int* boff = (int*)p;                              p += boff_bytes;
        int* deg  = (int*)p;

        int cblocks = (N * (FEAT / 4) + 255) / 256;
        convert_kernel<<<cblocks, 256, 0, stream>>>((const float4*)x, xbf,
                                                    N * (FEAT / 4));
        count_kernel<<<nchunk, 256, 0, stream>>>(receiver, sub, E, nbuck, epb);
        colscan_kernel<<<nbuck, 256, 0, stream>>>(sub, tot, nbuck, nchunk);
        scan_kernel<<<1, 1024, 0, stream>>>(tot, boff, nbuck);
        bucket_scatter_kernel<<<nchunk, 256, 0, stream>>>(
            sender, receiver, edge_len, log_scale, filter_w, filter_b,
            sub, boff, buf, E, nbuck, epb);
        bucket_sort_aggregate_kernel<<<nbuck, 256, 0, stream>>>(
            (const uint4*)xbf, buf, boff, agg_bf, deg, N);
        int fblocks = (N + 63) / 64;
        finalize_kernel<<<fblocks, 256, 0, stream>>>(x, (const uint4*)agg_bf, deg,
                                                     W_mix, out, N);
    } else {
        float* agg = (float*)d_ws;
        float* degf = agg + (size_t)N * FEAT;
        hipMemsetAsync(agg, 0, ((size_t)N * FEAT + N) * sizeof(float), stream);
        int sblocks = (E * 32 + 255) / 256;
        scatter_fallback<<<sblocks, 256, 0, stream>>>(
            (const float4*)x, sender, receiver, edge_len,
            log_scale, filter_w, filter_b, agg, degf, E);
        finalize_fallback<<<512, 256, 0, stream>>>(x, agg, degf, W_mix, out, N);
    }
}